// Round 1
// baseline (772.320 us; speedup 1.0000x reference)
//
#include <hip/hip_runtime.h>
#include <math.h>

// Packed variable-length softmax over rows.
// Static shape (from reference): SEQ_LEN=(1024,2048,512,1536), HEAD_NUM=16.
// Row-space layout (row = one softmax row of length s):
//   seg0: rows [0,     16384)  s=1024  base elem      0
//   seg1: rows [16384, 49152)  s=2048  base elem 16777216
//   seg2: rows [49152, 57344)  s=512   base elem 83886080
//   seg3: rows [57344, 81920)  s=1536  base elem 88080384
// Total rows 81920, total elems 125829120.

#define NROWS 81920

__global__ __launch_bounds__(256) void fast_softmax_kernel(
    const float* __restrict__ x, float* __restrict__ out) {
    const int row = blockIdx.x;

    int s, r, base;
    if (row < 16384)      { s = 1024; base = 0;        r = row;         }
    else if (row < 49152) { s = 2048; base = 16777216; r = row - 16384; }
    else if (row < 57344) { s = 512;  base = 83886080; r = row - 49152; }
    else                  { s = 1536; base = 88080384; r = row - 57344; }

    const int elem0 = base + r * s;                 // fits in int (<2^27)
    const float4* __restrict__ rowp = (const float4*)(x + elem0);
    float4* __restrict__ outp = (float4*)(out + elem0);
    const int nv4 = s >> 2;                         // 128..512 float4 per row
    const int tid = threadIdx.x;

    // ---- load whole row into registers (<=2 float4/thread), local max ----
    float4 v[2];
    float lmax = -INFINITY;
    int cnt = 0;
    #pragma unroll 2
    for (int i = tid; i < nv4; i += 256) {
        float4 t = rowp[i];
        v[cnt++] = t;
        lmax = fmaxf(lmax, fmaxf(fmaxf(t.x, t.y), fmaxf(t.z, t.w)));
    }

    // ---- block reduce max (4 waves) ----
    __shared__ float smax[4];
    __shared__ float ssum[4];
    #pragma unroll
    for (int off = 32; off > 0; off >>= 1)
        lmax = fmaxf(lmax, __shfl_xor(lmax, off, 64));
    const int wid  = tid >> 6;
    const int lane = tid & 63;
    if (lane == 0) smax[wid] = lmax;
    __syncthreads();
    const float m = fmaxf(fmaxf(smax[0], smax[1]), fmaxf(smax[2], smax[3]));

    // ---- exp in-register, local sum ----
    float lsum = 0.0f;
    #pragma unroll
    for (int k = 0; k < cnt; ++k) {
        float4 t = v[k];
        t.x = __expf(t.x - m);
        t.y = __expf(t.y - m);
        t.z = __expf(t.z - m);
        t.w = __expf(t.w - m);
        v[k] = t;
        lsum += (t.x + t.y) + (t.z + t.w);
    }

    // ---- block reduce sum ----
    #pragma unroll
    for (int off = 32; off > 0; off >>= 1)
        lsum += __shfl_xor(lsum, off, 64);
    if (lane == 0) ssum[wid] = lsum;
    __syncthreads();
    const float total = (ssum[0] + ssum[1]) + (ssum[2] + ssum[3]);
    const float inv = 1.0f / total;

    // ---- scale + store (vectorized, coalesced) ----
    cnt = 0;
    #pragma unroll 2
    for (int i = tid; i < nv4; i += 256) {
        float4 t = v[cnt++];
        t.x *= inv; t.y *= inv; t.z *= inv; t.w *= inv;
        outp[i] = t;
    }
}

extern "C" void kernel_launch(void* const* d_in, const int* in_sizes, int n_in,
                              void* d_out, int out_size, void* d_ws, size_t ws_size,
                              hipStream_t stream) {
    const float* x = (const float*)d_in[0];
    float* out = (float*)d_out;
    fast_softmax_kernel<<<NROWS, 256, 0, stream>>>(x, out);
}